// Round 17
// baseline (203.327 us; speedup 1.0000x reference)
//
#include <hip/hip_runtime.h>
#include <hip/hip_bf16.h>
#include <stdint.h>

// Problem dims (fixed): B=2, L=S=2048, C=1024, H=16, HD=64
// qk scale = HD^-0.25 * sqrt(log2(e))  (both operands -> logits carry HD^-0.5 * log2e, use exp2)

typedef __attribute__((ext_vector_type(8))) short bf16x8;
typedef __attribute__((ext_vector_type(4))) float f32x4;
typedef __attribute__((ext_vector_type(16))) float f32x16;
typedef __attribute__((ext_vector_type(4))) unsigned int u32x4;
typedef __attribute__((ext_vector_type(2))) unsigned int u32x2;
typedef __bf16 bf16_2 __attribute__((ext_vector_type(2)));

typedef const __attribute__((address_space(1))) unsigned int gu32;
typedef __attribute__((address_space(3))) unsigned int lu32;

__device__ __forceinline__ unsigned short f2bf(float f) {
  unsigned int u = __builtin_bit_cast(unsigned int, f);
  u += 0x7fffu + ((u >> 16) & 1u);       // round-to-nearest-even
  return (unsigned short)(u >> 16);
}

// packed f32x2 -> bf16x2 via scalar casts -> native v_cvt_pk_bf16_f32 (m240)
__device__ __forceinline__ unsigned int cvtpk(float lo, float hi_) {
  bf16_2 t = { (__bf16)lo, (__bf16)hi_ };
  return __builtin_bit_cast(unsigned int, t);
}

__device__ __forceinline__ unsigned short f2bf_hw(float f) {
  return __builtin_bit_cast(unsigned short, (__bf16)f);
}

// ---------------- f32 -> bf16 conversion: x0 ‖ x1 ‖ Wqk ‖ Wv ‖ Wm in ONE launch ------
__global__ void cvt_all(const float* __restrict__ x0, const float* __restrict__ x1,
                        const float* __restrict__ w0, const float* __restrict__ w1,
                        const float* __restrict__ w2,
                        unsigned short* __restrict__ xb, unsigned short* __restrict__ wb) {
  long bid = blockIdx.x;
  const float* src; unsigned short* dst; long i;
  if (bid < 4096) {
    int y = (int)(bid >> 11);
    src = y ? x1 : x0;
    dst = xb + (long)y * 4194304;
    i = (long)(bid & 2047) * 2048 + threadIdx.x * 8;
  } else {
    int r = (int)(bid - 4096);
    int y = r >> 9;
    src = (y == 0) ? w0 : ((y == 1) ? w1 : w2);
    dst = wb + (long)y * 1048576;
    i = (long)(r & 511) * 2048 + threadIdx.x * 8;
  }
  float4 a = *(const float4*)(src + i);
  float4 b = *(const float4*)(src + i + 4);
  union { unsigned short u[8]; bf16x8 v; } r;
  r.u[0] = f2bf(a.x); r.u[1] = f2bf(a.y); r.u[2] = f2bf(a.z); r.u[3] = f2bf(a.w);
  r.u[4] = f2bf(b.x); r.u[5] = f2bf(b.y); r.u[6] = f2bf(b.z); r.u[7] = f2bf(b.w);
  *(bf16x8*)(dst + i) = r.v;
}

// ============ 8-phase GEMM machinery (T3+T4; r13/r14-proven) ============
// A-side geometry shared: BM=256, K-stride 1024, BK=64.
// sA regions: [buf][mh] of [128 rowpos][64 k] bf16 (16KB) at smem + (buf*2+mh)*8192.
// k-slot swizzle: dest slot d at rowpos p holds k-slot d^(p&7) (both-sides involution).

#define QSTAGEA(BUF, MH, TT)                                                              \
  {                                                                                       \
    long kc = (long)(TT) * 64 + sslot * 8;                                                \
    const unsigned short* s0 = Ag + (long)(bm + (MH) * 64 + srow) * 1024 + kc;            \
    const unsigned short* s1 = Ag + (long)(bm + 128 + (MH) * 64 + srow) * 1024 + kc;      \
    __builtin_amdgcn_global_load_lds((gu32*)s0, (lu32*)(smem + ((BUF)*2+(MH))*8192 + dbase), 16, 0, 0);        \
    __builtin_amdgcn_global_load_lds((gu32*)s1, (lu32*)(smem + ((BUF)*2+(MH))*8192 + 4096 + dbase), 16, 0, 0); \
  }

#define QSTAGEB(BUF, NH, TT)                                                              \
  {                                                                                       \
    long kc = (long)(TT) * 64 + sslot * 8;                                                \
    const unsigned short* s0 = Bg + (long)(bnn + ((srow >> 5) * 64) + (NH) * 32 + (srow & 31)) * 1024 + kc;        \
    const unsigned short* s1 = Bg + (long)(bnn + (((64 + srow) >> 5) * 64) + (NH) * 32 + (srow & 31)) * 1024 + kc; \
    __builtin_amdgcn_global_load_lds((gu32*)s0, (lu32*)(smem + 32768 + ((BUF)*2+(NH))*8192 + dbase), 16, 0, 0);        \
    __builtin_amdgcn_global_load_lds((gu32*)s1, (lu32*)(smem + 32768 + ((BUF)*2+(NH))*8192 + 4096 + dbase), 16, 0, 0); \
  }

#define QCOMPUTE(RBUF, MH, NH)                                                            \
  {                                                                                       \
    const unsigned short* Ar = smem + ((RBUF)*2+(MH))*8192 + (wr * 64 + il) * 64;         \
    const unsigned short* Br = smem + 32768 + ((RBUF)*2+(NH))*8192 + (wc * 32 + il) * 64; \
    bf16x8 av[4][2], bv[2][2];                                                            \
    _Pragma("unroll")                                                                     \
    for (int mp = 0; mp < 4; ++mp)                                                        \
      _Pragma("unroll")                                                                   \
      for (int ks = 0; ks < 2; ++ks)                                                      \
        av[mp][ks] = *(const bf16x8*)(Ar + mp * 1024 + (((ks * 4 + g) ^ sw) * 8));        \
    _Pragma("unroll")                                                                     \
    for (int np = 0; np < 2; ++np)                                                        \
      _Pragma("unroll")                                                                   \
      for (int ks = 0; ks < 2; ++ks)                                                      \
        bv[np][ks] = *(const bf16x8*)(Br + np * 1024 + (((ks * 4 + g) ^ sw) * 8));        \
    _Pragma("unroll")                                                                     \
    for (int mp = 0; mp < 4; ++mp)                                                        \
      _Pragma("unroll")                                                                   \
      for (int np = 0; np < 2; ++np) {                                                    \
        acc[(MH)*4+mp][(NH)*2+np] = __builtin_amdgcn_mfma_f32_16x16x32_bf16(av[mp][0], bv[np][0], acc[(MH)*4+mp][(NH)*2+np], 0, 0, 0); \
        acc[(MH)*4+mp][(NH)*2+np] = __builtin_amdgcn_mfma_f32_16x16x32_bf16(av[mp][1], bv[np][1], acc[(MH)*4+mp][(NH)*2+np], 0, 0, 0); \
      }                                                                                   \
  }

#define QEND(W4, N4)                                                                      \
  {                                                                                       \
    if (W4) asm volatile("s_waitcnt vmcnt(" #N4 ")" ::: "memory");                        \
    asm volatile("" ::: "memory");                                                        \
    __builtin_amdgcn_s_barrier();                                                         \
    asm volatile("" ::: "memory");                                                        \
  }

// ---- fused qk+v projection GEMM: 256x256, B = wb [2048][1024] (Wqk ‖ Wv) ----
__global__ __launch_bounds__(512, 2)
void gemm_qkv8(const unsigned short* __restrict__ Ag, const unsigned short* __restrict__ Bg,
               unsigned short* __restrict__ C0, unsigned short* __restrict__ vt, float scale0) {
  extern __shared__ unsigned short smem[];   // 128 KB
  const int tid = threadIdx.x;
  const int lane = tid & 63, wid = tid >> 6;
  const int il = lane & 15, g = lane >> 4;
  const int wr = wid >> 2, wc = wid & 3;
  const int sw = il & 7;
  const int bm = blockIdx.y * 256, bnn = blockIdx.x * 256;

  const int srow = tid >> 3;
  const int sslot = (tid & 7) ^ ((tid >> 3) & 7);
  const int dbase = (tid >> 6) * 512;

  f32x4 acc[8][4];
#pragma unroll
  for (int m = 0; m < 8; ++m)
#pragma unroll
    for (int n = 0; n < 4; ++n) acc[m][n] = (f32x4){0.f, 0.f, 0.f, 0.f};

  QSTAGEA(0, 0, 0); QSTAGEA(0, 1, 0); QSTAGEB(0, 0, 0); QSTAGEB(0, 1, 0);
  QSTAGEB(1, 0, 1); QSTAGEA(1, 1, 1);
  __syncthreads();

#pragma unroll 1
  for (int i = 0; i < 8; ++i) {
    const int t1 = 2 * i + 1, t2 = (2 * i + 2) & 15, t3 = (2 * i + 3) & 15;
    QSTAGEA(1, 0, t1); QCOMPUTE(0, 0, 0); QEND(0, 0);   // P1
    QSTAGEB(1, 1, t1); QCOMPUTE(0, 1, 0); QEND(0, 0);   // P2
    QSTAGEB(0, 0, t2); QCOMPUTE(0, 1, 1); QEND(0, 0);   // P3
    QSTAGEA(0, 1, t2); QCOMPUTE(0, 0, 1); QEND(1, 4);   // P4 (vmcnt 4)
    QSTAGEA(0, 0, t2); QCOMPUTE(1, 0, 0); QEND(0, 0);   // P5
    QSTAGEB(0, 1, t2); QCOMPUTE(1, 1, 0); QEND(0, 0);   // P6
    QSTAGEB(1, 0, t3); QCOMPUTE(1, 1, 1); QEND(0, 0);   // P7
    QSTAGEA(1, 1, t3); QCOMPUTE(1, 0, 1); QEND(1, 4);   // P8 (vmcnt 4)
  }
  __syncthreads();   // full drain; LDS free for reuse

  if (bnn < 1024) {
#pragma unroll
    for (int m = 0; m < 8; ++m) {
      long row0 = bm + wr * 128 + m * 16 + g * 4;
#pragma unroll
      for (int n = 0; n < 4; ++n) {
        long col = bnn + wc * 64 + n * 16 + il;
#pragma unroll
        for (int r = 0; r < 4; ++r)
          C0[(row0 + r) * 1024 + col] = f2bf(acc[m][n][r] * scale0);
      }
    }
  } else {
    unsigned short (*T)[264] = (unsigned short (*)[264])smem;
    const int s = bm >> 11;
#pragma unroll 1
    for (int p = 0; p < 2; ++p) {
      if ((wc >> 1) == p) {
#pragma unroll
        for (int m = 0; m < 8; ++m) {
          int rl = wr * 128 + m * 16 + g * 4;
#pragma unroll
          for (int n = 0; n < 4; ++n) {
            int cl = (wc & 1) * 64 + n * 16 + il;
            u32x2 pk = { cvtpk(acc[m][n][0], acc[m][n][1]), cvtpk(acc[m][n][2], acc[m][n][3]) };
            *(u32x2*)&T[cl][rl] = pk;
          }
        }
      }
      __syncthreads();
      int cl2 = tid & 127, portion = tid >> 7;
      int col = (bnn - 1024) + p * 128 + cl2;
      unsigned short* dst = vt + (((long)(s * 16 + (col >> 6))) * 64 + (col & 63)) * 2048
                               + (bm & 2047) + portion * 64;
#pragma unroll
      for (int j = 0; j < 8; ++j)
        *(bf16x8*)(dst + j * 8) = *(const bf16x8*)&T[cl2][portion * 64 + j * 8];
      __syncthreads();
    }
  }
}

// ---- merge GEMM: 8-phase BM=256, BN=128 variant (f32 out, scale 1) ----
#define MSTAGEB(BUF, NH, TT)                                                              \
  {                                                                                       \
    long kc = (long)(TT) * 64 + sslot * 8;                                                \
    const unsigned short* s0 = Bg + (long)(bnn + ((srow >> 4) * 32) + (NH) * 16 + (srow & 15)) * 1024 + kc; \
    __builtin_amdgcn_global_load_lds((gu32*)s0, (lu32*)(smem + 32768 + ((BUF)*2+(NH))*4096 + dbase2), 16, 0, 0); \
  }

#define MCOMPUTE(RBUF, MH, NH)                                                            \
  {                                                                                       \
    const unsigned short* Ar = smem + ((RBUF)*2+(MH))*8192 + (wr * 64 + il) * 64;         \
    const unsigned short* Br = smem + 32768 + ((RBUF)*2+(NH))*4096 + (wc * 16 + il) * 64; \
    bf16x8 av[4][2], bv[2];                                                               \
    _Pragma("unroll")                                                                     \
    for (int mp = 0; mp < 4; ++mp)                                                        \
      _Pragma("unroll")                                                                   \
      for (int ks = 0; ks < 2; ++ks)                                                      \
        av[mp][ks] = *(const bf16x8*)(Ar + mp * 1024 + (((ks * 4 + g) ^ sw) * 8));        \
    _Pragma("unroll")                                                                     \
    for (int ks = 0; ks < 2; ++ks)                                                        \
      bv[ks] = *(const bf16x8*)(Br + (((ks * 4 + g) ^ sw) * 8));                          \
    _Pragma("unroll")                                                                     \
    for (int mp = 0; mp < 4; ++mp) {                                                      \
      acc[(MH)*4+mp][(NH)] = __builtin_amdgcn_mfma_f32_16x16x32_bf16(av[mp][0], bv[0], acc[(MH)*4+mp][(NH)], 0, 0, 0); \
      acc[(MH)*4+mp][(NH)] = __builtin_amdgcn_mfma_f32_16x16x32_bf16(av[mp][1], bv[1], acc[(MH)*4+mp][(NH)], 0, 0, 0); \
    }                                                                                     \
  }

__global__ __launch_bounds__(512, 2)
void gemm_merge8(const unsigned short* __restrict__ Ag, const unsigned short* __restrict__ Bg,
                 float* __restrict__ C) {
  extern __shared__ unsigned short smem[];   // 96 KB
  const int tid = threadIdx.x;
  const int lane = tid & 63, wid = tid >> 6;
  const int il = lane & 15, g = lane >> 4;
  const int wr = wid >> 2, wc = wid & 3;
  const int sw = il & 7;
  const int bm = blockIdx.y * 256, bnn = blockIdx.x * 128;

  const int srow = tid >> 3;
  const int sslot = (tid & 7) ^ ((tid >> 3) & 7);
  const int dbase = (tid >> 6) * 512;
  const int dbase2 = tid * 8;

  f32x4 acc[8][2];
#pragma unroll
  for (int m = 0; m < 8; ++m)
#pragma unroll
    for (int n = 0; n < 2; ++n) acc[m][n] = (f32x4){0.f, 0.f, 0.f, 0.f};

  QSTAGEA(0, 0, 0); QSTAGEA(0, 1, 0); MSTAGEB(0, 0, 0); MSTAGEB(0, 1, 0);
  MSTAGEB(1, 0, 1); QSTAGEA(1, 1, 1);
  __syncthreads();

#pragma unroll 1
  for (int i = 0; i < 8; ++i) {
    const int t1 = 2 * i + 1, t2 = (2 * i + 2) & 15, t3 = (2 * i + 3) & 15;
    QSTAGEA(1, 0, t1); MCOMPUTE(0, 0, 0); QEND(0, 0);   // P1
    MSTAGEB(1, 1, t1); MCOMPUTE(0, 1, 0); QEND(0, 0);   // P2
    MSTAGEB(0, 0, t2); MCOMPUTE(0, 1, 1); QEND(0, 0);   // P3
    QSTAGEA(0, 1, t2); MCOMPUTE(0, 0, 1); QEND(1, 3);   // P4 (vmcnt 3)
    QSTAGEA(0, 0, t2); MCOMPUTE(1, 0, 0); QEND(0, 0);   // P5
    MSTAGEB(0, 1, t2); MCOMPUTE(1, 1, 0); QEND(0, 0);   // P6
    MSTAGEB(1, 0, t3); MCOMPUTE(1, 1, 1); QEND(0, 0);   // P7
    QSTAGEA(1, 1, t3); MCOMPUTE(1, 0, 1); QEND(1, 3);   // P8 (vmcnt 3)
  }
  __syncthreads();

#pragma unroll
  for (int m = 0; m < 8; ++m) {
    long row0 = bm + wr * 128 + m * 16 + g * 4;
#pragma unroll
    for (int n = 0; n < 2; ++n) {
      long col = bnn + wc * 32 + n * 16 + il;
#pragma unroll
      for (int r = 0; r < 4; ++r)
        C[(row0 + r) * 1024 + col] = acc[m][n][r];
    }
  }
}

// ---------------- fused bidirectional flash attention (32x32 swapped, LDS 2-phase) ----
// r17: k-half software pipeline. r16 counters: VALU 49% + MFMA 38% with ~no overlap
// (phase-pure order alternates pipes). New order interleaves the two independent
// k-halves: QK0, QK1, exp0+pack0, PV(ks0,1), exp1+pack1, PV(ks2,3) — each MFMA
// cluster executes under the other half's VALU cluster. Same math, same registers,
// same sync. lacc folds per-half (FP-order change only).
__global__ __launch_bounds__(256, 4)
void attn_kernel(const unsigned short* __restrict__ qk,
                 const unsigned short* __restrict__ vt,
                 unsigned short* __restrict__ o) {
  __shared__ unsigned short sK[2][4096];
  __shared__ unsigned short sV[2][4096];
  int bid = blockIdx.x;
  int lb = (bid & 7) * 128 + (bid >> 3);  // XCD-chunked swizzle (1024 % 8 == 0, bijective)
  int tid = threadIdx.x;
  int w = tid >> 6, lane = tid & 63;
  int u = lb * 4 + w;
  int dir = u >> 11, bh = (u >> 6) & 31, qu = u & 63;
  int b = bh >> 4, h = bh & 15;
  int q = lane & 31, hi = lane >> 5;

  long qrow0 = (dir ? 4096L : 0L) + b * 2048L + (long)qu * 32L;
  long krow0 = (dir ? 0L : 4096L) + b * 2048L;
  int vs = dir ? b : 2 + b;
  long vrow0 = (long)(vs * 16 + h) * 64;

  const unsigned short* Qp = qk + (qrow0 + q) * 1024 + h * 64 + hi * 8;

  int srow = tid >> 3;
  int sc = ((tid & 7) * 8) ^ ((srow & 7) << 3);
  const unsigned short* kg = qk + (krow0 + srow) * 1024 + h * 64 + sc;
  const unsigned short* vg = vt + (vrow0 + srow) * 2048 + sc;
  const int wbase = w * 512;

  // hoisted swizzled LDS fragment pointers (buf0; buf1 = +4096 elems)
  const int cswz = (q & 7) << 3;
  const unsigned short* kR[8];
  const unsigned short* vR[8];
#pragma unroll
  for (int kb = 0; kb < 2; ++kb)
#pragma unroll
    for (int ds = 0; ds < 4; ++ds)
      kR[kb * 4 + ds] = &sK[0][(kb * 32 + q) * 64 + ((ds * 16 + hi * 8) ^ cswz)];
#pragma unroll
  for (int ks = 0; ks < 4; ++ks)
#pragma unroll
    for (int dn = 0; dn < 2; ++dn)
      vR[ks * 2 + dn] = &sV[0][(dn * 32 + q) * 64 + ((ks * 16 + hi * 8) ^ cswz)];

#define STAGE(BUF)                                                                       \
  {                                                                                      \
    __builtin_amdgcn_global_load_lds((gu32*)kg,                (lu32*)(sK[BUF] + wbase),        16, 0, 0); \
    __builtin_amdgcn_global_load_lds((gu32*)(kg + 32 * 1024),  (lu32*)(sK[BUF] + wbase + 2048), 16, 0, 0); \
    __builtin_amdgcn_global_load_lds((gu32*)vg,                (lu32*)(sV[BUF] + wbase),        16, 0, 0); \
    __builtin_amdgcn_global_load_lds((gu32*)(vg + 32 * 2048),  (lu32*)(sV[BUF] + wbase + 2048), 16, 0, 0); \
    kg += 65536; vg += 64;                                                               \
  }

  bf16x8 qf[4];
#pragma unroll
  for (int ds = 0; ds < 4; ++ds)
    qf[ds] = *(const bf16x8*)(Qp + ds * 16);

  f32x16 z16;
#pragma unroll
  for (int j = 0; j < 16; ++j) z16[j] = 0.f;
  f32x16 accO[2];
  accO[0] = z16; accO[1] = z16;
  float lacc = 0.f;

// half-tile helpers: pack one st half -> pa pair, PV over its 2 k-slices
#define PACK2(ST, PA0, PA1)                                                              \
  {                                                                                      \
    unsigned int a0 = cvtpk(ST[0], ST[1]),  a1 = cvtpk(ST[2], ST[3]);                    \
    unsigned int b0 = cvtpk(ST[4], ST[5]),  b1 = cvtpk(ST[6], ST[7]);                    \
    unsigned int c0 = cvtpk(ST[8], ST[9]),  c1 = cvtpk(ST[10], ST[11]);                  \
    unsigned int d0 = cvtpk(ST[12], ST[13]), d1 = cvtpk(ST[14], ST[15]);                 \
    u32x2 r0 = __builtin_amdgcn_permlane32_swap(a0, b0, false, false);                   \
    u32x2 r1 = __builtin_amdgcn_permlane32_swap(a1, b1, false, false);                   \
    u32x2 r2 = __builtin_amdgcn_permlane32_swap(c0, d0, false, false);                   \
    u32x2 r3 = __builtin_amdgcn_permlane32_swap(c1, d1, false, false);                   \
    u32x4 u0 = {r0[0], r1[0], r0[1], r1[1]};                                             \
    u32x4 u1 = {r2[0], r3[0], r2[1], r3[1]};                                             \
    PA0 = __builtin_bit_cast(bf16x8, u0);                                                \
    PA1 = __builtin_bit_cast(bf16x8, u1);                                                \
  }

// BODY(BUF): interleaved k-half pipeline (see header comment)
#define BODY(BUF)                                                                        \
  {                                                                                      \
    bf16x8 kf[8], vf[8];                                                                 \
    _Pragma("unroll")                                                                    \
    for (int j = 0; j < 8; ++j) kf[j] = *(const bf16x8*)(kR[j] + (BUF) * 4096);          \
    _Pragma("unroll")                                                                    \
    for (int j = 0; j < 8; ++j) vf[j] = *(const bf16x8*)(vR[j] + (BUF) * 4096);          \
    f32x16 st0 = __builtin_amdgcn_mfma_f32_32x32x16_bf16(kf[0], qf[0], z16, 0, 0, 0);    \
    f32x16 st1 = __builtin_amdgcn_mfma_f32_32x32x16_bf16(kf[4], qf[0], z16, 0, 0, 0);    \
    _Pragma("unroll")                                                                    \
    for (int ds = 1; ds < 4; ++ds)                                                       \
      st0 = __builtin_amdgcn_mfma_f32_32x32x16_bf16(kf[ds], qf[ds], st0, 0, 0, 0);       \
    _Pragma("unroll")                                                                    \
    for (int ds = 1; ds < 4; ++ds)                                                       \
      st1 = __builtin_amdgcn_mfma_f32_32x32x16_bf16(kf[4 + ds], qf[ds], st1, 0, 0, 0);   \
    /* half 0: exp + sum + pack + PV(ks0,1) — overlaps st1 chain latency */              \
    _Pragma("unroll")                                                                    \
    for (int j = 0; j < 16; ++j) st0[j] = __builtin_amdgcn_exp2f(st0[j]);                \
    {                                                                                    \
      float s0 = 0.f, s1 = 0.f, s2 = 0.f, s3 = 0.f;                                      \
      _Pragma("unroll")                                                                  \
      for (int j = 0; j < 4; ++j) {                                                      \
        s0 += st0[j]; s1 += st0[4 + j]; s2 += st0[8 + j]; s3 += st0[12 + j];             \
      }                                                                                  \
      lacc += (s0 + s1) + (s2 + s3);                                                     \
    }                                                                                    \
    bf16x8 pa0, pa1;                                                                     \
    PACK2(st0, pa0, pa1);                                                                \
    accO[0] = __builtin_amdgcn_mfma_f32_32x32x16_bf16(pa0, vf[0], accO[0], 0, 0, 0);     \
    accO[1] = __builtin_amdgcn_mfma_f32_32x32x16_bf16(pa0, vf[1], accO[1], 0, 0, 0);     \
    accO[0] = __builtin_amdgcn_mfma_f32_32x32x16_bf16(pa1, vf[2], accO[0], 0, 0, 0);     \
    accO[1] = __builtin_amdgcn_mfma_f32_32x32x16_bf16(pa1, vf[3], accO[1], 0, 0, 0);     \
    /* half 1: exp + sum + pack — overlaps PV(ks0,1) pipe time */                        \
    _Pragma("unroll")                                                                    \
    for (int j = 0; j < 16; ++j) st1[j] = __builtin_amdgcn_exp2f(st1[j]);                \
    {                                                                                    \
      float s0 = 0.f, s1 = 0.f, s2 = 0.f, s3 = 0.f;                                      \
      _Pragma("unroll")                                                                  \
      for (int j = 0; j < 4; ++j) {                                                      \
        s0 += st1[j]; s1 += st1[4 + j]; s2 += st1[8 + j]; s3 += st1[12 + j];             \
      }                                                                                  \
      lacc += (s0 + s1) + (s2 + s3);                                                     \
    }                                                                                    \
    bf16x8 pa2, pa3;                                                                     \
    PACK2(st1, pa2, pa3);                                                                \
    accO[0] = __builtin_amdgcn_mfma_f32_32x32x16_bf16(pa2, vf[4], accO[0], 0, 0, 0);     \
    accO[1] = __builtin_amdgcn_mfma_f32_32x32x16_bf16(pa2, vf[5], accO[1], 0, 0, 0);     \
    accO[0] = __builtin_amdgcn_mfma_f32_32x32x16_bf16(pa3, vf[6], accO[0], 0, 0, 0);     \
    accO[1] = __builtin_amdgcn_mfma_f32_32x32x16_bf16(pa3, vf[7], accO[1], 0, 0, 0);     \
  }

  STAGE(0);
  __syncthreads();                        // tile 0 staged

#pragma unroll 1
  for (int t2 = 0; t2 < 16; ++t2) {
    STAGE(1);
    BODY(0);
    __syncthreads();
    if (t2 < 15) STAGE(0);
    BODY(1);
    __syncthreads();
  }
#undef STAGE
#undef BODY
#undef PACK2

  // epilogue: l[q] = own-half + other-half; normalize rows (O row = (r&3)+8(r>>2)+4hi)
  float tot = lacc + __shfl_xor(lacc, 32, 64);
  float inv = 1.f / tot;
#pragma unroll
  for (int r = 0; r < 16; ++r) {
    int row = (r & 3) + 8 * (r >> 2) + 4 * hi;
    float invr = __shfl(inv, row, 64);
    long orow = qrow0 + row;
#pragma unroll
    for (int dn = 0; dn < 2; ++dn)
      o[orow * 1024 + h * 64 + dn * 32 + q] = f2bf_hw(accO[dn][r] * invr);
  }
}

// ---------------- launch ----------------
extern "C" void kernel_launch(void* const* d_in, const int* in_sizes, int n_in,
                              void* d_out, int out_size, void* d_ws, size_t ws_size,
                              hipStream_t stream) {
  const float* x0 = (const float*)d_in[0];
  const float* x1 = (const float*)d_in[1];
  const float* Wqk = (const float*)d_in[2];
  const float* Wv = (const float*)d_in[3];
  const float* Wm = (const float*)d_in[4];
  float* out = (float*)d_out;

  const long NX = 4194304;  // B*L*C per stream
  const long NW = 1048576;  // C*C
  unsigned short* xb  = (unsigned short*)d_ws;  // [8192][1024] bf16  (x0 ‖ x1)
  unsigned short* wb  = xb + 2 * NX;            // Wqk ‖ Wv ‖ Wmerge bf16
  unsigned short* qkb = wb + 3 * NW;            // [8192][1024] qk (scaled)
  unsigned short* vb  = qkb + 2 * NX;           // [8192][1024] attention out o
  unsigned short* vtb = vb + 2 * NX;            // [4096][2048] per-head V^T (from gemm_qkv8)

  cvt_all<<<5632, 256, 0, stream>>>(x0, x1, Wqk, Wv, Wm, xb, wb);

  const float sqk = 0.35355339059327373f * 1.2011224087864498f; // HD^-0.25 * sqrt(log2 e)
  gemm_qkv8<<<dim3(8, 32), 512, 131072, stream>>>(xb, wb, qkb, vtb, sqk);
  attn_kernel<<<1024, 256, 0, stream>>>(qkb, vtb, vb);
  gemm_merge8<<<dim3(8, 32), 512, 98304, stream>>>(vb, wb + 2 * NW, out);
}

// Round 18
// 153.507 us; speedup vs baseline: 1.3245x; 1.3245x over previous
//
#include <hip/hip_runtime.h>
#include <hip/hip_bf16.h>
#include <stdint.h>

// Problem dims (fixed): B=2, L=S=2048, C=1024, H=16, HD=64
// qk scale = HD^-0.25 * sqrt(log2(e))  (both operands -> logits carry HD^-0.5 * log2e, use exp2)

typedef __attribute__((ext_vector_type(8))) short bf16x8;
typedef __attribute__((ext_vector_type(4))) float f32x4;
typedef __attribute__((ext_vector_type(16))) float f32x16;
typedef __attribute__((ext_vector_type(4))) unsigned int u32x4;
typedef __attribute__((ext_vector_type(2))) unsigned int u32x2;
typedef __bf16 bf16_2 __attribute__((ext_vector_type(2)));

typedef const __attribute__((address_space(1))) unsigned int gu32;
typedef __attribute__((address_space(3))) unsigned int lu32;

__device__ __forceinline__ unsigned short f2bf(float f) {
  unsigned int u = __builtin_bit_cast(unsigned int, f);
  u += 0x7fffu + ((u >> 16) & 1u);       // round-to-nearest-even
  return (unsigned short)(u >> 16);
}

// packed f32x2 -> bf16x2 via scalar casts -> native v_cvt_pk_bf16_f32 (m240)
__device__ __forceinline__ unsigned int cvtpk(float lo, float hi_) {
  bf16_2 t = { (__bf16)lo, (__bf16)hi_ };
  return __builtin_bit_cast(unsigned int, t);
}

__device__ __forceinline__ unsigned short f2bf_hw(float f) {
  return __builtin_bit_cast(unsigned short, (__bf16)f);
}

// ---------------- f32 -> bf16 conversion: x0 ‖ x1 ‖ Wqk ‖ Wv ‖ Wm in ONE launch ------
__global__ void cvt_all(const float* __restrict__ x0, const float* __restrict__ x1,
                        const float* __restrict__ w0, const float* __restrict__ w1,
                        const float* __restrict__ w2,
                        unsigned short* __restrict__ xb, unsigned short* __restrict__ wb) {
  long bid = blockIdx.x;
  const float* src; unsigned short* dst; long i;
  if (bid < 4096) {
    int y = (int)(bid >> 11);
    src = y ? x1 : x0;
    dst = xb + (long)y * 4194304;
    i = (long)(bid & 2047) * 2048 + threadIdx.x * 8;
  } else {
    int r = (int)(bid - 4096);
    int y = r >> 9;
    src = (y == 0) ? w0 : ((y == 1) ? w1 : w2);
    dst = wb + (long)y * 1048576;
    i = (long)(r & 511) * 2048 + threadIdx.x * 8;
  }
  float4 a = *(const float4*)(src + i);
  float4 b = *(const float4*)(src + i + 4);
  union { unsigned short u[8]; bf16x8 v; } r;
  r.u[0] = f2bf(a.x); r.u[1] = f2bf(a.y); r.u[2] = f2bf(a.z); r.u[3] = f2bf(a.w);
  r.u[4] = f2bf(b.x); r.u[5] = f2bf(b.y); r.u[6] = f2bf(b.z); r.u[7] = f2bf(b.w);
  *(bf16x8*)(dst + i) = r.v;
}

// ============ 8-phase GEMM machinery (T3+T4; r13/r14-proven) ============
// A-side geometry shared: BM=256, K-stride 1024, BK=64.
// sA regions: [buf][mh] of [128 rowpos][64 k] bf16 (16KB) at smem + (buf*2+mh)*8192.
// k-slot swizzle: dest slot d at rowpos p holds k-slot d^(p&7) (both-sides involution).

#define QSTAGEA(BUF, MH, TT)                                                              \
  {                                                                                       \
    long kc = (long)(TT) * 64 + sslot * 8;                                                \
    const unsigned short* s0 = Ag + (long)(bm + (MH) * 64 + srow) * 1024 + kc;            \
    const unsigned short* s1 = Ag + (long)(bm + 128 + (MH) * 64 + srow) * 1024 + kc;      \
    __builtin_amdgcn_global_load_lds((gu32*)s0, (lu32*)(smem + ((BUF)*2+(MH))*8192 + dbase), 16, 0, 0);        \
    __builtin_amdgcn_global_load_lds((gu32*)s1, (lu32*)(smem + ((BUF)*2+(MH))*8192 + 4096 + dbase), 16, 0, 0); \
  }

#define QSTAGEB(BUF, NH, TT)                                                              \
  {                                                                                       \
    long kc = (long)(TT) * 64 + sslot * 8;                                                \
    const unsigned short* s0 = Bg + (long)(bnn + ((srow >> 5) * 64) + (NH) * 32 + (srow & 31)) * 1024 + kc;        \
    const unsigned short* s1 = Bg + (long)(bnn + (((64 + srow) >> 5) * 64) + (NH) * 32 + (srow & 31)) * 1024 + kc; \
    __builtin_amdgcn_global_load_lds((gu32*)s0, (lu32*)(smem + 32768 + ((BUF)*2+(NH))*8192 + dbase), 16, 0, 0);        \
    __builtin_amdgcn_global_load_lds((gu32*)s1, (lu32*)(smem + 32768 + ((BUF)*2+(NH))*8192 + 4096 + dbase), 16, 0, 0); \
  }

#define QCOMPUTE(RBUF, MH, NH)                                                            \
  {                                                                                       \
    const unsigned short* Ar = smem + ((RBUF)*2+(MH))*8192 + (wr * 64 + il) * 64;         \
    const unsigned short* Br = smem + 32768 + ((RBUF)*2+(NH))*8192 + (wc * 32 + il) * 64; \
    bf16x8 av[4][2], bv[2][2];                                                            \
    _Pragma("unroll")                                                                     \
    for (int mp = 0; mp < 4; ++mp)                                                        \
      _Pragma("unroll")                                                                   \
      for (int ks = 0; ks < 2; ++ks)                                                      \
        av[mp][ks] = *(const bf16x8*)(Ar + mp * 1024 + (((ks * 4 + g) ^ sw) * 8));        \
    _Pragma("unroll")                                                                     \
    for (int np = 0; np < 2; ++np)                                                        \
      _Pragma("unroll")                                                                   \
      for (int ks = 0; ks < 2; ++ks)                                                      \
        bv[np][ks] = *(const bf16x8*)(Br + np * 1024 + (((ks * 4 + g) ^ sw) * 8));        \
    _Pragma("unroll")                                                                     \
    for (int mp = 0; mp < 4; ++mp)                                                        \
      _Pragma("unroll")                                                                   \
      for (int np = 0; np < 2; ++np) {                                                    \
        acc[(MH)*4+mp][(NH)*2+np] = __builtin_amdgcn_mfma_f32_16x16x32_bf16(av[mp][0], bv[np][0], acc[(MH)*4+mp][(NH)*2+np], 0, 0, 0); \
        acc[(MH)*4+mp][(NH)*2+np] = __builtin_amdgcn_mfma_f32_16x16x32_bf16(av[mp][1], bv[np][1], acc[(MH)*4+mp][(NH)*2+np], 0, 0, 0); \
      }                                                                                   \
  }

#define QEND(W4, N4)                                                                      \
  {                                                                                       \
    if (W4) asm volatile("s_waitcnt vmcnt(" #N4 ")" ::: "memory");                        \
    asm volatile("" ::: "memory");                                                        \
    __builtin_amdgcn_s_barrier();                                                         \
    asm volatile("" ::: "memory");                                                        \
  }

// ---- fused qk+v projection GEMM: 256x256, B = wb [2048][1024] (Wqk ‖ Wv) ----
__global__ __launch_bounds__(512, 2)
void gemm_qkv8(const unsigned short* __restrict__ Ag, const unsigned short* __restrict__ Bg,
               unsigned short* __restrict__ C0, unsigned short* __restrict__ vt, float scale0) {
  extern __shared__ unsigned short smem[];   // 128 KB
  const int tid = threadIdx.x;
  const int lane = tid & 63, wid = tid >> 6;
  const int il = lane & 15, g = lane >> 4;
  const int wr = wid >> 2, wc = wid & 3;
  const int sw = il & 7;
  const int bm = blockIdx.y * 256, bnn = blockIdx.x * 256;

  const int srow = tid >> 3;
  const int sslot = (tid & 7) ^ ((tid >> 3) & 7);
  const int dbase = (tid >> 6) * 512;

  f32x4 acc[8][4];
#pragma unroll
  for (int m = 0; m < 8; ++m)
#pragma unroll
    for (int n = 0; n < 4; ++n) acc[m][n] = (f32x4){0.f, 0.f, 0.f, 0.f};

  QSTAGEA(0, 0, 0); QSTAGEA(0, 1, 0); QSTAGEB(0, 0, 0); QSTAGEB(0, 1, 0);
  QSTAGEB(1, 0, 1); QSTAGEA(1, 1, 1);
  __syncthreads();

#pragma unroll 1
  for (int i = 0; i < 8; ++i) {
    const int t1 = 2 * i + 1, t2 = (2 * i + 2) & 15, t3 = (2 * i + 3) & 15;
    QSTAGEA(1, 0, t1); QCOMPUTE(0, 0, 0); QEND(0, 0);   // P1
    QSTAGEB(1, 1, t1); QCOMPUTE(0, 1, 0); QEND(0, 0);   // P2
    QSTAGEB(0, 0, t2); QCOMPUTE(0, 1, 1); QEND(0, 0);   // P3
    QSTAGEA(0, 1, t2); QCOMPUTE(0, 0, 1); QEND(1, 4);   // P4 (vmcnt 4)
    QSTAGEA(0, 0, t2); QCOMPUTE(1, 0, 0); QEND(0, 0);   // P5
    QSTAGEB(0, 1, t2); QCOMPUTE(1, 1, 0); QEND(0, 0);   // P6
    QSTAGEB(1, 0, t3); QCOMPUTE(1, 1, 1); QEND(0, 0);   // P7
    QSTAGEA(1, 1, t3); QCOMPUTE(1, 0, 1); QEND(1, 4);   // P8 (vmcnt 4)
  }
  __syncthreads();   // full drain; LDS free for reuse

  if (bnn < 1024) {
#pragma unroll
    for (int m = 0; m < 8; ++m) {
      long row0 = bm + wr * 128 + m * 16 + g * 4;
#pragma unroll
      for (int n = 0; n < 4; ++n) {
        long col = bnn + wc * 64 + n * 16 + il;
#pragma unroll
        for (int r = 0; r < 4; ++r)
          C0[(row0 + r) * 1024 + col] = f2bf(acc[m][n][r] * scale0);
      }
    }
  } else {
    unsigned short (*T)[264] = (unsigned short (*)[264])smem;
    const int s = bm >> 11;
#pragma unroll 1
    for (int p = 0; p < 2; ++p) {
      if ((wc >> 1) == p) {
#pragma unroll
        for (int m = 0; m < 8; ++m) {
          int rl = wr * 128 + m * 16 + g * 4;
#pragma unroll
          for (int n = 0; n < 4; ++n) {
            int cl = (wc & 1) * 64 + n * 16 + il;
            u32x2 pk = { cvtpk(acc[m][n][0], acc[m][n][1]), cvtpk(acc[m][n][2], acc[m][n][3]) };
            *(u32x2*)&T[cl][rl] = pk;
          }
        }
      }
      __syncthreads();
      int cl2 = tid & 127, portion = tid >> 7;
      int col = (bnn - 1024) + p * 128 + cl2;
      unsigned short* dst = vt + (((long)(s * 16 + (col >> 6))) * 64 + (col & 63)) * 2048
                               + (bm & 2047) + portion * 64;
#pragma unroll
      for (int j = 0; j < 8; ++j)
        *(bf16x8*)(dst + j * 8) = *(const bf16x8*)&T[cl2][portion * 64 + j * 8];
      __syncthreads();
    }
  }
}

// ---- merge GEMM: 8-phase BM=256, BN=128 variant (f32 out, scale 1) ----
#define MSTAGEB(BUF, NH, TT)                                                              \
  {                                                                                       \
    long kc = (long)(TT) * 64 + sslot * 8;                                                \
    const unsigned short* s0 = Bg + (long)(bnn + ((srow >> 4) * 32) + (NH) * 16 + (srow & 15)) * 1024 + kc; \
    __builtin_amdgcn_global_load_lds((gu32*)s0, (lu32*)(smem + 32768 + ((BUF)*2+(NH))*4096 + dbase2), 16, 0, 0); \
  }

#define MCOMPUTE(RBUF, MH, NH)                                                            \
  {                                                                                       \
    const unsigned short* Ar = smem + ((RBUF)*2+(MH))*8192 + (wr * 64 + il) * 64;         \
    const unsigned short* Br = smem + 32768 + ((RBUF)*2+(NH))*4096 + (wc * 16 + il) * 64; \
    bf16x8 av[4][2], bv[2];                                                               \
    _Pragma("unroll")                                                                     \
    for (int mp = 0; mp < 4; ++mp)                                                        \
      _Pragma("unroll")                                                                   \
      for (int ks = 0; ks < 2; ++ks)                                                      \
        av[mp][ks] = *(const bf16x8*)(Ar + mp * 1024 + (((ks * 4 + g) ^ sw) * 8));        \
    _Pragma("unroll")                                                                     \
    for (int ks = 0; ks < 2; ++ks)                                                        \
      bv[ks] = *(const bf16x8*)(Br + (((ks * 4 + g) ^ sw) * 8));                          \
    _Pragma("unroll")                                                                     \
    for (int mp = 0; mp < 4; ++mp) {                                                      \
      acc[(MH)*4+mp][(NH)] = __builtin_amdgcn_mfma_f32_16x16x32_bf16(av[mp][0], bv[0], acc[(MH)*4+mp][(NH)], 0, 0, 0); \
      acc[(MH)*4+mp][(NH)] = __builtin_amdgcn_mfma_f32_16x16x32_bf16(av[mp][1], bv[1], acc[(MH)*4+mp][(NH)], 0, 0, 0); \
    }                                                                                     \
  }

__global__ __launch_bounds__(512, 2)
void gemm_merge8(const unsigned short* __restrict__ Ag, const unsigned short* __restrict__ Bg,
                 float* __restrict__ C) {
  extern __shared__ unsigned short smem[];   // 96 KB
  const int tid = threadIdx.x;
  const int lane = tid & 63, wid = tid >> 6;
  const int il = lane & 15, g = lane >> 4;
  const int wr = wid >> 2, wc = wid & 3;
  const int sw = il & 7;
  const int bm = blockIdx.y * 256, bnn = blockIdx.x * 128;

  const int srow = tid >> 3;
  const int sslot = (tid & 7) ^ ((tid >> 3) & 7);
  const int dbase = (tid >> 6) * 512;
  const int dbase2 = tid * 8;

  f32x4 acc[8][2];
#pragma unroll
  for (int m = 0; m < 8; ++m)
#pragma unroll
    for (int n = 0; n < 2; ++n) acc[m][n] = (f32x4){0.f, 0.f, 0.f, 0.f};

  QSTAGEA(0, 0, 0); QSTAGEA(0, 1, 0); MSTAGEB(0, 0, 0); MSTAGEB(0, 1, 0);
  MSTAGEB(1, 0, 1); QSTAGEA(1, 1, 1);
  __syncthreads();

#pragma unroll 1
  for (int i = 0; i < 8; ++i) {
    const int t1 = 2 * i + 1, t2 = (2 * i + 2) & 15, t3 = (2 * i + 3) & 15;
    QSTAGEA(1, 0, t1); MCOMPUTE(0, 0, 0); QEND(0, 0);   // P1
    MSTAGEB(1, 1, t1); MCOMPUTE(0, 1, 0); QEND(0, 0);   // P2
    MSTAGEB(0, 0, t2); MCOMPUTE(0, 1, 1); QEND(0, 0);   // P3
    QSTAGEA(0, 1, t2); MCOMPUTE(0, 0, 1); QEND(1, 3);   // P4 (vmcnt 3)
    QSTAGEA(0, 0, t2); MCOMPUTE(1, 0, 0); QEND(0, 0);   // P5
    MSTAGEB(0, 1, t2); MCOMPUTE(1, 1, 0); QEND(0, 0);   // P6
    MSTAGEB(1, 0, t3); MCOMPUTE(1, 1, 1); QEND(0, 0);   // P7
    QSTAGEA(1, 1, t3); MCOMPUTE(1, 0, 1); QEND(1, 3);   // P8 (vmcnt 3)
  }
  __syncthreads();

#pragma unroll
  for (int m = 0; m < 8; ++m) {
    long row0 = bm + wr * 128 + m * 16 + g * 4;
#pragma unroll
    for (int n = 0; n < 2; ++n) {
      long col = bnn + wc * 32 + n * 16 + il;
#pragma unroll
      for (int r = 0; r < 4; ++r)
        C[(row0 + r) * 1024 + col] = acc[m][n][r];
    }
  }
}

// ---------------- fused bidirectional flash attention (32x32 swapped, LDS 2-phase) ----
// r18: exact revert to the r16 BODY (80.2us proven). r17's k-half interleave extended
// st1's live range across half0's compute -> loop-carried scratch spills (FETCH/WRITE
// +100MB, 144us). Lesson (3rd occurrence): in this kernel, any reorder that keeps an
// f32x16 live across another compute cluster spills. Phase-pure order stands.
__global__ __launch_bounds__(256, 4)
void attn_kernel(const unsigned short* __restrict__ qk,
                 const unsigned short* __restrict__ vt,
                 unsigned short* __restrict__ o) {
  __shared__ unsigned short sK[2][4096];
  __shared__ unsigned short sV[2][4096];
  int bid = blockIdx.x;
  int lb = (bid & 7) * 128 + (bid >> 3);  // XCD-chunked swizzle (1024 % 8 == 0, bijective)
  int tid = threadIdx.x;
  int w = tid >> 6, lane = tid & 63;
  int u = lb * 4 + w;
  int dir = u >> 11, bh = (u >> 6) & 31, qu = u & 63;
  int b = bh >> 4, h = bh & 15;
  int q = lane & 31, hi = lane >> 5;

  long qrow0 = (dir ? 4096L : 0L) + b * 2048L + (long)qu * 32L;
  long krow0 = (dir ? 0L : 4096L) + b * 2048L;
  int vs = dir ? b : 2 + b;
  long vrow0 = (long)(vs * 16 + h) * 64;

  const unsigned short* Qp = qk + (qrow0 + q) * 1024 + h * 64 + hi * 8;

  int srow = tid >> 3;
  int sc = ((tid & 7) * 8) ^ ((srow & 7) << 3);
  const unsigned short* kg = qk + (krow0 + srow) * 1024 + h * 64 + sc;
  const unsigned short* vg = vt + (vrow0 + srow) * 2048 + sc;
  const int wbase = w * 512;

  // hoisted, loop-invariant swizzled LDS fragment pointers (buf0; buf1 = +4096 elems)
  const int cswz = (q & 7) << 3;
  const unsigned short* kR[8];
  const unsigned short* vR[8];
#pragma unroll
  for (int kb = 0; kb < 2; ++kb)
#pragma unroll
    for (int ds = 0; ds < 4; ++ds)
      kR[kb * 4 + ds] = &sK[0][(kb * 32 + q) * 64 + ((ds * 16 + hi * 8) ^ cswz)];
#pragma unroll
  for (int ks = 0; ks < 4; ++ks)
#pragma unroll
    for (int dn = 0; dn < 2; ++dn)
      vR[ks * 2 + dn] = &sV[0][(dn * 32 + q) * 64 + ((ks * 16 + hi * 8) ^ cswz)];

#define STAGE(BUF)                                                                       \
  {                                                                                      \
    __builtin_amdgcn_global_load_lds((gu32*)kg,                (lu32*)(sK[BUF] + wbase),        16, 0, 0); \
    __builtin_amdgcn_global_load_lds((gu32*)(kg + 32 * 1024),  (lu32*)(sK[BUF] + wbase + 2048), 16, 0, 0); \
    __builtin_amdgcn_global_load_lds((gu32*)vg,                (lu32*)(sV[BUF] + wbase),        16, 0, 0); \
    __builtin_amdgcn_global_load_lds((gu32*)(vg + 32 * 2048),  (lu32*)(sV[BUF] + wbase + 2048), 16, 0, 0); \
    kg += 65536; vg += 64;                                                               \
  }

  bf16x8 qf[4];
#pragma unroll
  for (int ds = 0; ds < 4; ++ds)
    qf[ds] = *(const bf16x8*)(Qp + ds * 16);

  f32x16 z16;
#pragma unroll
  for (int j = 0; j < 16; ++j) z16[j] = 0.f;
  f32x16 accO[2];
  accO[0] = z16; accO[1] = z16;
  float lacc = 0.f;

// BODY(BUF): full tile compute on buffer BUF (compile-time) — ds_read base+imm only.
#define BODY(BUF)                                                                        \
  {                                                                                      \
    bf16x8 kf[8], vf[8];                                                                 \
    _Pragma("unroll")                                                                    \
    for (int j = 0; j < 8; ++j) kf[j] = *(const bf16x8*)(kR[j] + (BUF) * 4096);          \
    _Pragma("unroll")                                                                    \
    for (int j = 0; j < 8; ++j) vf[j] = *(const bf16x8*)(vR[j] + (BUF) * 4096);          \
    f32x16 st0 = __builtin_amdgcn_mfma_f32_32x32x16_bf16(kf[0], qf[0], z16, 0, 0, 0);    \
    f32x16 st1 = __builtin_amdgcn_mfma_f32_32x32x16_bf16(kf[4], qf[0], z16, 0, 0, 0);    \
    _Pragma("unroll")                                                                    \
    for (int ds = 1; ds < 4; ++ds)                                                       \
      st0 = __builtin_amdgcn_mfma_f32_32x32x16_bf16(kf[ds], qf[ds], st0, 0, 0, 0);       \
    _Pragma("unroll")                                                                    \
    for (int ds = 1; ds < 4; ++ds)                                                       \
      st1 = __builtin_amdgcn_mfma_f32_32x32x16_bf16(kf[4 + ds], qf[ds], st1, 0, 0, 0);   \
    _Pragma("unroll")                                                                    \
    for (int j = 0; j < 16; ++j) {                                                       \
      st0[j] = __builtin_amdgcn_exp2f(st0[j]);                                           \
      st1[j] = __builtin_amdgcn_exp2f(st1[j]);                                           \
    }                                                                                    \
    float s0 = 0.f, s1 = 0.f, s2 = 0.f, s3 = 0.f;                                        \
    _Pragma("unroll")                                                                    \
    for (int j = 0; j < 4; ++j) {                                                        \
      s0 += st0[j]      + st1[j];                                                        \
      s1 += st0[4 + j]  + st1[4 + j];                                                    \
      s2 += st0[8 + j]  + st1[8 + j];                                                    \
      s3 += st0[12 + j] + st1[12 + j];                                                   \
    }                                                                                    \
    lacc += (s0 + s1) + (s2 + s3);                                                       \
    bf16x8 pa[4];                                                                        \
    _Pragma("unroll")                                                                    \
    for (int ks = 0; ks < 4; ++ks) {                                                     \
      int m0 = (ks & 1) * 8;                                                             \
      unsigned int a0, a1, b0, b1;                                                       \
      if (ks < 2) {                                                                      \
        a0 = cvtpk(st0[m0],     st0[m0 + 1]); a1 = cvtpk(st0[m0 + 2], st0[m0 + 3]);      \
        b0 = cvtpk(st0[m0 + 4], st0[m0 + 5]); b1 = cvtpk(st0[m0 + 6], st0[m0 + 7]);      \
      } else {                                                                           \
        a0 = cvtpk(st1[m0],     st1[m0 + 1]); a1 = cvtpk(st1[m0 + 2], st1[m0 + 3]);      \
        b0 = cvtpk(st1[m0 + 4], st1[m0 + 5]); b1 = cvtpk(st1[m0 + 6], st1[m0 + 7]);      \
      }                                                                                  \
      u32x2 r0 = __builtin_amdgcn_permlane32_swap(a0, b0, false, false);                 \
      u32x2 r1 = __builtin_amdgcn_permlane32_swap(a1, b1, false, false);                 \
      u32x4 uu = {r0[0], r1[0], r0[1], r1[1]};                                           \
      pa[ks] = __builtin_bit_cast(bf16x8, uu);                                           \
    }                                                                                    \
    _Pragma("unroll")                                                                    \
    for (int ks = 0; ks < 4; ++ks)                                                       \
      _Pragma("unroll")                                                                  \
      for (int dn = 0; dn < 2; ++dn)                                                     \
        accO[dn] = __builtin_amdgcn_mfma_f32_32x32x16_bf16(pa[ks], vf[ks * 2 + dn], accO[dn], 0, 0, 0); \
  }

  STAGE(0);
  __syncthreads();                        // tile 0 staged

#pragma unroll 1
  for (int t2 = 0; t2 < 16; ++t2) {
    // tile 2*t2 on buf0; stage tile 2*t2+1 into buf1 (always valid: <= 31)
    STAGE(1);
    BODY(0);
    __syncthreads();
    // tile 2*t2+1 on buf1; stage tile 2*t2+2 into buf0 if it exists
    if (t2 < 15) STAGE(0);
    BODY(1);
    __syncthreads();
  }
#undef STAGE
#undef BODY

  // epilogue: l[q] = own-half + other-half; normalize rows (O row = (r&3)+8(r>>2)+4hi)
  float tot = lacc + __shfl_xor(lacc, 32, 64);
  float inv = 1.f / tot;
#pragma unroll
  for (int r = 0; r < 16; ++r) {
    int row = (r & 3) + 8 * (r >> 2) + 4 * hi;
    float invr = __shfl(inv, row, 64);
    long orow = qrow0 + row;
#pragma unroll
    for (int dn = 0; dn < 2; ++dn)
      o[orow * 1024 + h * 64 + dn * 32 + q] = f2bf_hw(accO[dn][r] * invr);
  }
}

// ---------------- launch ----------------
extern "C" void kernel_launch(void* const* d_in, const int* in_sizes, int n_in,
                              void* d_out, int out_size, void* d_ws, size_t ws_size,
                              hipStream_t stream) {
  const float* x0 = (const float*)d_in[0];
  const float* x1 = (const float*)d_in[1];
  const float* Wqk = (const float*)d_in[2];
  const float* Wv = (const float*)d_in[3];
  const float* Wm = (const float*)d_in[4];
  float* out = (float*)d_out;

  const long NX = 4194304;  // B*L*C per stream
  const long NW = 1048576;  // C*C
  unsigned short* xb  = (unsigned short*)d_ws;  // [8192][1024] bf16  (x0 ‖ x1)
  unsigned short* wb  = xb + 2 * NX;            // Wqk ‖ Wv ‖ Wmerge bf16
  unsigned short* qkb = wb + 3 * NW;            // [8192][1024] qk (scaled)
  unsigned short* vb  = qkb + 2 * NX;           // [8192][1024] attention out o
  unsigned short* vtb = vb + 2 * NX;            // [4096][2048] per-head V^T (from gemm_qkv8)

  cvt_all<<<5632, 256, 0, stream>>>(x0, x1, Wqk, Wv, Wm, xb, wb);

  const float sqk = 0.35355339059327373f * 1.2011224087864498f; // HD^-0.25 * sqrt(log2 e)
  gemm_qkv8<<<dim3(8, 32), 512, 131072, stream>>>(xb, wb, qkb, vtb, sqk);
  attn_kernel<<<1024, 256, 0, stream>>>(qkb, vtb, vb);
  gemm_merge8<<<dim3(8, 32), 512, 98304, stream>>>(vb, wb + 2 * NW, out);
}